// Round 1
// baseline (114.804 us; speedup 1.0000x reference)
//
#include <hip/hip_runtime.h>
#include <hip/hip_bf16.h>

#define BB 16
#define NN 64
#define AA 8400
#define CC 20
#define TOPKK 13

struct OvRes { float ov; int inside; };

// Shared by K1 and K2 so recomputed overlaps are bitwise identical.
__device__ __attribute__((noinline)) OvRes masked_overlap(
    float gx1, float gy1, float gx2, float gy2,
    float px1, float py1, float px2, float py2,
    float ax, float ay)
{
    float d = fminf(fminf(ax - gx1, ay - gy1), fminf(gx2 - ax, gy2 - ay));
    int inside = d > 1e-9f;
    float ov = 0.0f;
    if (inside) {
        const float eps = 1e-7f;
        float w1 = gx2 - gx1, h1 = gy2 - gy1;
        float w2 = px2 - px1, h2 = py2 - py1;
        float ix = fmaxf(fminf(gx2, px2) - fmaxf(gx1, px1), 0.0f);
        float iy = fmaxf(fminf(gy2, py2) - fmaxf(gy1, py1), 0.0f);
        float inter = ix * iy;
        float uni = w1 * h1 + w2 * h2 - inter + eps;
        float iou = inter / uni;
        float cw = fmaxf(gx2, px2) - fminf(gx1, px1);
        float ch = fmaxf(gy2, py2) - fminf(gy1, py1);
        float c2 = cw * cw + ch * ch + eps;
        float dx = px1 + px2 - gx1 - gx2;
        float dy = py1 + py2 - gy1 - gy2;
        float rho2 = (dx * dx + dy * dy) * 0.25f;
        float at = atanf(w2 / (h2 + eps)) - atanf(w1 / (h1 + eps));
        float v = 0.40528473456935109f * (at * at);
        float alpha = v / (v - iou + 1.0000001f);
        float ciou = iou - (rho2 / c2 + v * alpha);
        ov = fmaxf(ciou, 0.0f);
    }
    OvRes r; r.ov = ov; r.inside = inside; return r;
}

// K1: one block per (b,n). Build align row in LDS, top-13, emit candidates.
__global__ __launch_bounds__(256) void k1_build(
    const float* __restrict__ pd_scores, const float4* __restrict__ pd_bboxes,
    const float2* __restrict__ anc, const int* __restrict__ gt_labels, int lab_stride,
    const float4* __restrict__ gt_bboxes, const float* __restrict__ mask_gt,
    unsigned long long* __restrict__ pos_bits,
    int* __restrict__ cand_idx, float* __restrict__ cand_ov,
    float* __restrict__ cand_al, int* __restrict__ cand_cnt)
{
    int row = blockIdx.x;          // b*NN + n
    int b = row >> 6, n = row & 63;
    int tid = threadIdx.x;

    __shared__ float s_align[AA];
    __shared__ float s_rval[256];
    __shared__ int   s_ridx[256];
    __shared__ int   s_selidx[TOPKK];
    __shared__ float s_selval[TOPKK];
    __shared__ int   s_cnt;

    float mg = mask_gt[row];
    if (mg <= 0.0f) { if (tid == 0) cand_cnt[row] = 0; return; }

    float4 g = gt_bboxes[row];
    int label = gt_labels[row * lab_stride];
    const float4* pb = pd_bboxes + (size_t)b * AA;
    const float* ps = pd_scores + (size_t)b * AA * CC + label;

    for (int a = tid; a < AA; a += 256) {
        float4 p = pb[a];
        float2 ap = anc[a];
        OvRes r = masked_overlap(g.x, g.y, g.z, g.w, p.x, p.y, p.z, p.w, ap.x, ap.y);
        float score = r.inside ? ps[(size_t)a * CC] : 0.0f;
        float o2 = r.ov * r.ov;
        float o6 = o2 * o2 * o2;
        s_align[a] = score * o6;
    }
    __syncthreads();

    // iterative top-13: max value, ties -> smallest index (matches lax.top_k)
    for (int k = 0; k < TOPKK; ++k) {
        float best = -2.0f; int bi = AA;
        for (int a = tid; a < AA; a += 256) {
            float v = s_align[a];
            if (v > best) { best = v; bi = a; }
        }
        s_rval[tid] = best; s_ridx[tid] = bi;
        __syncthreads();
        for (int s = 128; s > 0; s >>= 1) {
            if (tid < s) {
                float v2 = s_rval[tid + s]; int i2 = s_ridx[tid + s];
                float v1 = s_rval[tid];     int i1 = s_ridx[tid];
                if (v2 > v1 || (v2 == v1 && i2 < i1)) { s_rval[tid] = v2; s_ridx[tid] = i2; }
            }
            __syncthreads();
        }
        if (tid == 0) {
            int sel = s_ridx[0];
            s_selidx[k] = sel;
            s_selval[k] = s_rval[0];
            s_align[sel] = -1.0f;   // remove; all real values >= 0
        }
        __syncthreads();
    }

    if (tid == 0) s_cnt = 0;
    __syncthreads();
    if (tid < TOPKK) {
        int a = s_selidx[tid];
        float4 p = pb[a];
        float2 ap = anc[a];
        OvRes r = masked_overlap(g.x, g.y, g.z, g.w, p.x, p.y, p.z, p.w, ap.x, ap.y);
        if (r.inside) {   // mask_pos = topk & in_gts & mask_gt (mg>0 known)
            int slot = atomicAdd(&s_cnt, 1);
            cand_idx[row * TOPKK + slot] = a;
            cand_ov[row * TOPKK + slot]  = r.ov;
            cand_al[row * TOPKK + slot]  = s_selval[tid];
            atomicOr(&pos_bits[(size_t)b * AA + a], 1ull << n);
        }
    }
    __syncthreads();
    if (tid == 0) cand_cnt[row] = s_cnt;
}

// K2: resolve multi-assigned anchors: keep only argmax_n overlaps (first-max).
__global__ __launch_bounds__(256) void k2_filter(
    const float4* __restrict__ pd_bboxes, const float2* __restrict__ anc,
    const float4* __restrict__ gt_bboxes, const float* __restrict__ mask_gt,
    unsigned long long* __restrict__ pos_bits)
{
    int i = blockIdx.x * 256 + threadIdx.x;
    if (i >= BB * AA) return;
    unsigned long long bits = pos_bits[i];
    if (__popcll(bits) <= 1) return;
    int b = i / AA, a = i % AA;
    float4 p = pd_bboxes[i];
    float2 ap = anc[a];
    float best = -1.0f; int bn = 0;
    for (int n = 0; n < NN; ++n) {
        float ov = 0.0f;
        if (mask_gt[b * NN + n] > 0.0f) {
            float4 g = gt_bboxes[b * NN + n];
            OvRes r = masked_overlap(g.x, g.y, g.z, g.w, p.x, p.y, p.z, p.w, ap.x, ap.y);
            ov = r.ov;
        }
        if (ov > best) { best = ov; bn = n; }
    }
    pos_bits[i] = bits & (1ull << bn);
}

// K3: per-(b,n) pos_align / pos_ov over surviving candidates.
__global__ __launch_bounds__(256) void k3_rowmax(
    const unsigned long long* __restrict__ pos_bits, const int* __restrict__ cand_idx,
    const float* __restrict__ cand_ov, const float* __restrict__ cand_al,
    const int* __restrict__ cand_cnt,
    float* __restrict__ pos_align, float* __restrict__ pos_ovv)
{
    int row = blockIdx.x * 256 + threadIdx.x;
    if (row >= BB * NN) return;
    int b = row >> 6, n = row & 63;
    int cnt = cand_cnt[row];
    float pa = 0.0f, po = 0.0f;
    for (int i = 0; i < cnt; ++i) {
        int a = cand_idx[row * TOPKK + i];
        if ((pos_bits[(size_t)b * AA + a] >> n) & 1ull) {
            pa = fmaxf(pa, cand_al[row * TOPKK + i]);
            po = fmaxf(po, cand_ov[row * TOPKK + i]);
        }
    }
    pos_align[row] = pa;
    pos_ovv[row] = po;
}

// K4: final outputs.
__global__ __launch_bounds__(256) void k4_out(
    const unsigned long long* __restrict__ pos_bits, const int* __restrict__ gt_labels,
    int lab_stride, const float4* __restrict__ gt_bboxes,
    const int* __restrict__ cand_idx, const float* __restrict__ cand_al,
    const int* __restrict__ cand_cnt,
    const float* __restrict__ pos_align, const float* __restrict__ pos_ovv,
    float* __restrict__ out_labels, float* __restrict__ out_bboxes,
    float* __restrict__ out_scores, float* __restrict__ out_fg,
    float* __restrict__ out_tgt)
{
    int i = blockIdx.x * 256 + threadIdx.x;
    if (i >= BB * AA) return;
    int b = i / AA;
    unsigned long long bits = pos_bits[i];
    int fg = bits != 0ull;
    int tgt = fg ? (__ffsll((unsigned long long)bits) - 1) : 0;
    int row = b * NN + tgt;
    int label = gt_labels[row * lab_stride];
    label = label > 0 ? label : 0;
    float4 g = gt_bboxes[row];
    out_labels[i] = (float)label;
    ((float4*)out_bboxes)[i] = g;
    float norm = 0.0f;
    if (fg) {
        int cnt = cand_cnt[row];
        int a = i - b * AA;
        float al = 0.0f;
        for (int j = 0; j < cnt; ++j) {
            if (cand_idx[row * TOPKK + j] == a) { al = cand_al[row * TOPKK + j]; break; }
        }
        norm = (al * pos_ovv[row]) / (pos_align[row] + 1e-9f);
    }
    float* sc = out_scores + (size_t)i * CC;
    #pragma unroll
    for (int c = 0; c < CC; ++c) sc[c] = (c == label && fg) ? norm : 0.0f;
    out_fg[i] = fg ? 1.0f : 0.0f;
    out_tgt[i] = (float)tgt;
}

extern "C" void kernel_launch(void* const* d_in, const int* in_sizes, int n_in,
                              void* d_out, int out_size, void* d_ws, size_t ws_size,
                              hipStream_t stream) {
    const float*  pd_scores = (const float*)d_in[0];
    const float4* pd_bboxes = (const float4*)d_in[1];
    const float2* anc       = (const float2*)d_in[2];
    const int*    gt_labels = (const int*)d_in[3];
    const float4* gt_bboxes = (const float4*)d_in[4];
    const float*  mask_gt   = (const float*)d_in[5];
    int lab_stride = (in_sizes[3] == 2 * BB * NN) ? 2 : 1;  // int64 fallback

    const int BA = BB * AA;     // 134400
    const int BN = BB * NN;     // 1024

    char* ws = (char*)d_ws;
    unsigned long long* pos_bits = (unsigned long long*)ws;          size_t off = (size_t)BA * 8;
    int*   cand_idx  = (int*)(ws + off);   off += (size_t)BN * TOPKK * 4;
    float* cand_ov   = (float*)(ws + off); off += (size_t)BN * TOPKK * 4;
    float* cand_al   = (float*)(ws + off); off += (size_t)BN * TOPKK * 4;
    int*   cand_cnt  = (int*)(ws + off);   off += (size_t)BN * 4;
    float* pos_align = (float*)(ws + off); off += (size_t)BN * 4;
    float* pos_ovv   = (float*)(ws + off);

    float* out_labels = (float*)d_out;
    float* out_bboxes = out_labels + BA;
    float* out_scores = out_bboxes + (size_t)BA * 4;
    float* out_fg     = out_scores + (size_t)BA * CC;
    float* out_tgt    = out_fg + BA;

    hipMemsetAsync(pos_bits, 0, (size_t)BA * 8, stream);

    k1_build<<<BN, 256, 0, stream>>>(pd_scores, pd_bboxes, anc, gt_labels, lab_stride,
                                     gt_bboxes, mask_gt, pos_bits,
                                     cand_idx, cand_ov, cand_al, cand_cnt);
    k2_filter<<<(BA + 255) / 256, 256, 0, stream>>>(pd_bboxes, anc, gt_bboxes, mask_gt, pos_bits);
    k3_rowmax<<<(BN + 255) / 256, 256, 0, stream>>>(pos_bits, cand_idx, cand_ov, cand_al,
                                                    cand_cnt, pos_align, pos_ovv);
    k4_out<<<(BA + 255) / 256, 256, 0, stream>>>(pos_bits, gt_labels, lab_stride, gt_bboxes,
                                                 cand_idx, cand_al, cand_cnt, pos_align, pos_ovv,
                                                 out_labels, out_bboxes, out_scores, out_fg, out_tgt);
}

// Round 2
// 87.514 us; speedup vs baseline: 1.3118x; 1.3118x over previous
//
#include <hip/hip_runtime.h>
#include <hip/hip_bf16.h>

#define BB 16
#define NN 64
#define AA 8400
#define CC 20
#define TOPKK 13
#define CAP 1024

struct OvRes { float ov; int inside; };

// Shared by K1 and K2 so recomputed overlaps are bitwise identical.
// atanf hoisted out (precomputed tables) — at_pd/at_gt passed in.
__device__ __attribute__((noinline)) OvRes masked_overlap(
    float gx1, float gy1, float gx2, float gy2,
    float px1, float py1, float px2, float py2,
    float ax, float ay, float at_pd, float at_gt)
{
    float d = fminf(fminf(ax - gx1, ay - gy1), fminf(gx2 - ax, gy2 - ay));
    int inside = d > 1e-9f;
    float ov = 0.0f;
    if (inside) {
        const float eps = 1e-7f;
        float w1 = gx2 - gx1, h1 = gy2 - gy1;
        float w2 = px2 - px1, h2 = py2 - py1;
        float ix = fmaxf(fminf(gx2, px2) - fmaxf(gx1, px1), 0.0f);
        float iy = fmaxf(fminf(gy2, py2) - fmaxf(gy1, py1), 0.0f);
        float inter = ix * iy;
        float uni = w1 * h1 + w2 * h2 - inter + eps;
        float iou = inter / uni;
        float cw = fmaxf(gx2, px2) - fminf(gx1, px1);
        float ch = fmaxf(gy2, py2) - fminf(gy1, py1);
        float c2 = cw * cw + ch * ch + eps;
        float dx = px1 + px2 - gx1 - gx2;
        float dy = py1 + py2 - gy1 - gy2;
        float rho2 = (dx * dx + dy * dy) * 0.25f;
        float at = at_pd - at_gt;
        float v = 0.40528473456935109f * (at * at);
        float alpha = v / (v - iou + 1.0000001f);
        float ciou = iou - (rho2 / c2 + v * alpha);
        ov = fmaxf(ciou, 0.0f);
    }
    OvRes r; r.ov = ov; r.inside = inside; return r;
}

// K0: precompute atan tables. i < BB*AA: pd-side; i < BB*NN: gt-side.
__global__ __launch_bounds__(256) void k0_atan(
    const float4* __restrict__ pd_bboxes, const float4* __restrict__ gt_bboxes,
    float* __restrict__ atan_pd, float* __restrict__ atan_gt)
{
    int i = blockIdx.x * 256 + threadIdx.x;
    if (i < BB * AA) {
        float4 p = pd_bboxes[i];
        atan_pd[i] = atanf((p.z - p.x) / ((p.w - p.y) + 1e-7f));
    }
    if (i < BB * NN) {
        float4 g = gt_bboxes[i];
        atan_gt[i] = atanf((g.z - g.x) / ((g.w - g.y) + 1e-7f));
    }
}

// K1: one block per (b,n). Compact positive align entries, shuffle-reduce
// top-13, exact zero-tie path for p < 13.
__global__ __launch_bounds__(256) void k1_build(
    const float* __restrict__ pd_scores, const float4* __restrict__ pd_bboxes,
    const float2* __restrict__ anc, const int* __restrict__ gt_labels, int lab_stride,
    const float4* __restrict__ gt_bboxes, const float* __restrict__ mask_gt,
    const float* __restrict__ atan_pd, const float* __restrict__ atan_gt,
    unsigned long long* __restrict__ pos_bits,
    int* __restrict__ cand_idx, float* __restrict__ cand_ov,
    float* __restrict__ cand_al, int* __restrict__ cand_cnt)
{
    int row = blockIdx.x;          // b*NN + n
    int b = row >> 6, n = row & 63;
    int tid = threadIdx.x;

    __shared__ float s_val[CAP];
    __shared__ float s_ov[CAP];
    __shared__ int   s_aidx[CAP];
    __shared__ int   s_p;
    __shared__ float s_stash_al[32];
    __shared__ float s_stash_ov[32];
    __shared__ int   s_stash_in[32];
    __shared__ float s_wval[4];
    __shared__ int   s_waidx[4];
    __shared__ int   s_wslot[4];
    __shared__ float s_selal[TOPKK];
    __shared__ float s_selov[TOPKK];
    __shared__ int   s_selaidx[TOPKK];
    __shared__ int   s_nsel;

    float mg = mask_gt[row];
    if (mg <= 0.0f) { if (tid == 0) cand_cnt[row] = 0; return; }
    if (tid == 0) s_p = 0;
    __syncthreads();

    float4 g = gt_bboxes[row];
    float at_g = atan_gt[row];
    int label = gt_labels[row * lab_stride];
    const float4* pb = pd_bboxes + (size_t)b * AA;
    const float*  ps = pd_scores + (size_t)b * AA * CC + label;
    const float*  apd = atan_pd + (size_t)b * AA;

    for (int a = tid; a < AA; a += 256) {
        float4 p = pb[a];
        float2 apnt = anc[a];
        OvRes r = masked_overlap(g.x, g.y, g.z, g.w, p.x, p.y, p.z, p.w,
                                 apnt.x, apnt.y, apd[a], at_g);
        float score = r.inside ? ps[(size_t)a * CC] : 0.0f;
        float o2 = r.ov * r.ov;
        float al = score * (o2 * o2 * o2);
        if (al > 0.0f) {
            int slot = atomicAdd(&s_p, 1);
            if (slot < CAP) { s_val[slot] = al; s_ov[slot] = r.ov; s_aidx[slot] = a; }
        }
        if (a < 32) { s_stash_al[a] = al; s_stash_ov[a] = r.ov; s_stash_in[a] = r.inside; }
    }
    __syncthreads();

    int p = min(s_p, CAP);
    int nrounds = min(p, TOPKK);
    int lane = tid & 63, wv = tid >> 6;

    for (int k = 0; k < nrounds; ++k) {
        // local argmax over up to 4 owned slots (value desc, anchor-idx asc)
        float bv = -1.0f; int ba = 1 << 30; int bs = 0;
        #pragma unroll
        for (int j = 0; j < 4; ++j) {
            int slot = tid + j * 256;
            if (slot < p) {
                float v = s_val[slot];
                int ai = s_aidx[slot];
                if (v > bv || (v == bv && ai < ba)) { bv = v; ba = ai; bs = slot; }
            }
        }
        // 64-lane butterfly
        #pragma unroll
        for (int s2 = 32; s2 > 0; s2 >>= 1) {
            float v2 = __shfl_xor(bv, s2);
            int   a2 = __shfl_xor(ba, s2);
            int   sl = __shfl_xor(bs, s2);
            if (v2 > bv || (v2 == bv && a2 < ba)) { bv = v2; ba = a2; bs = sl; }
        }
        if (lane == 0) { s_wval[wv] = bv; s_waidx[wv] = ba; s_wslot[wv] = bs; }
        __syncthreads();
        if (tid == 0) {
            float Bv = s_wval[0]; int Ba = s_waidx[0]; int Bs = s_wslot[0];
            for (int w = 1; w < 4; ++w) {
                float v = s_wval[w]; int a2 = s_waidx[w]; int sl = s_wslot[w];
                if (v > Bv || (v == Bv && a2 < Ba)) { Bv = v; Ba = a2; Bs = sl; }
            }
            s_selal[k] = Bv; s_selov[k] = s_ov[Bs]; s_selaidx[k] = Ba;
            s_val[Bs] = -1.0f;   // remove
        }
        __syncthreads();
    }

    // p < 13: top_k admits zeros at smallest anchor indices. Among a in [0,32)
    // at least 13 zeros exist (p < 13 positives total). Emit only inside ones.
    if (tid == 0) {
        int nsel = nrounds;
        if (p < TOPKK) {
            int need = TOPKK - p;
            for (int a = 0; a < 32 && need > 0; ++a) {
                if (s_stash_al[a] == 0.0f) {
                    if (s_stash_in[a]) {
                        s_selal[nsel] = 0.0f;
                        s_selov[nsel] = s_stash_ov[a];
                        s_selaidx[nsel] = a;
                        nsel++;
                    }
                    need--;
                }
            }
        }
        s_nsel = nsel;
    }
    __syncthreads();

    int nsel = s_nsel;
    if (tid < nsel) {
        int a = s_selaidx[tid];
        cand_idx[row * TOPKK + tid] = a;
        cand_ov[row * TOPKK + tid]  = s_selov[tid];
        cand_al[row * TOPKK + tid]  = s_selal[tid];
        atomicOr(&pos_bits[(size_t)b * AA + a], 1ull << n);
    }
    if (tid == 0) cand_cnt[row] = nsel;
}

// K2: resolve multi-assigned anchors: keep only argmax_n overlaps (first-max).
__global__ __launch_bounds__(256) void k2_filter(
    const float4* __restrict__ pd_bboxes, const float2* __restrict__ anc,
    const float4* __restrict__ gt_bboxes, const float* __restrict__ mask_gt,
    const float* __restrict__ atan_pd, const float* __restrict__ atan_gt,
    unsigned long long* __restrict__ pos_bits)
{
    int i = blockIdx.x * 256 + threadIdx.x;
    if (i >= BB * AA) return;
    unsigned long long bits = pos_bits[i];
    if (__popcll(bits) <= 1) return;
    int b = i / AA, a = i % AA;
    float4 p = pd_bboxes[i];
    float2 ap = anc[a];
    float at_p = atan_pd[i];
    float best = -1.0f; int bn = 0;
    for (int n = 0; n < NN; ++n) {
        float ov = 0.0f;
        if (mask_gt[b * NN + n] > 0.0f) {
            float4 g = gt_bboxes[b * NN + n];
            OvRes r = masked_overlap(g.x, g.y, g.z, g.w, p.x, p.y, p.z, p.w,
                                     ap.x, ap.y, at_p, atan_gt[b * NN + n]);
            ov = r.ov;
        }
        if (ov > best) { best = ov; bn = n; }
    }
    pos_bits[i] = bits & (1ull << bn);
}

// K3: per-(b,n) pos_align / pos_ov over surviving candidates.
__global__ __launch_bounds__(256) void k3_rowmax(
    const unsigned long long* __restrict__ pos_bits, const int* __restrict__ cand_idx,
    const float* __restrict__ cand_ov, const float* __restrict__ cand_al,
    const int* __restrict__ cand_cnt,
    float* __restrict__ pos_align, float* __restrict__ pos_ovv)
{
    int row = blockIdx.x * 256 + threadIdx.x;
    if (row >= BB * NN) return;
    int b = row >> 6, n = row & 63;
    int cnt = cand_cnt[row];
    float pa = 0.0f, po = 0.0f;
    for (int i = 0; i < cnt; ++i) {
        int a = cand_idx[row * TOPKK + i];
        if ((pos_bits[(size_t)b * AA + a] >> n) & 1ull) {
            pa = fmaxf(pa, cand_al[row * TOPKK + i]);
            po = fmaxf(po, cand_ov[row * TOPKK + i]);
        }
    }
    pos_align[row] = pa;
    pos_ovv[row] = po;
}

// K4: final outputs.
__global__ __launch_bounds__(256) void k4_out(
    const unsigned long long* __restrict__ pos_bits, const int* __restrict__ gt_labels,
    int lab_stride, const float4* __restrict__ gt_bboxes,
    const int* __restrict__ cand_idx, const float* __restrict__ cand_al,
    const int* __restrict__ cand_cnt,
    const float* __restrict__ pos_align, const float* __restrict__ pos_ovv,
    float* __restrict__ out_labels, float* __restrict__ out_bboxes,
    float* __restrict__ out_scores, float* __restrict__ out_fg,
    float* __restrict__ out_tgt)
{
    int i = blockIdx.x * 256 + threadIdx.x;
    if (i >= BB * AA) return;
    int b = i / AA;
    unsigned long long bits = pos_bits[i];
    int fg = bits != 0ull;
    int tgt = fg ? (__ffsll((unsigned long long)bits) - 1) : 0;
    int row = b * NN + tgt;
    int label = gt_labels[row * lab_stride];
    label = label > 0 ? label : 0;
    float4 g = gt_bboxes[row];
    out_labels[i] = (float)label;
    ((float4*)out_bboxes)[i] = g;
    float norm = 0.0f;
    if (fg) {
        int cnt = cand_cnt[row];
        int a = i - b * AA;
        float al = 0.0f;
        for (int j = 0; j < cnt; ++j) {
            if (cand_idx[row * TOPKK + j] == a) { al = cand_al[row * TOPKK + j]; break; }
        }
        norm = (al * pos_ovv[row]) / (pos_align[row] + 1e-9f);
    }
    float* sc = out_scores + (size_t)i * CC;
    #pragma unroll
    for (int c = 0; c < CC; ++c) sc[c] = (c == label && fg) ? norm : 0.0f;
    out_fg[i] = fg ? 1.0f : 0.0f;
    out_tgt[i] = (float)tgt;
}

extern "C" void kernel_launch(void* const* d_in, const int* in_sizes, int n_in,
                              void* d_out, int out_size, void* d_ws, size_t ws_size,
                              hipStream_t stream) {
    const float*  pd_scores = (const float*)d_in[0];
    const float4* pd_bboxes = (const float4*)d_in[1];
    const float2* anc       = (const float2*)d_in[2];
    const int*    gt_labels = (const int*)d_in[3];
    const float4* gt_bboxes = (const float4*)d_in[4];
    const float*  mask_gt   = (const float*)d_in[5];
    int lab_stride = (in_sizes[3] == 2 * BB * NN) ? 2 : 1;  // int64 fallback

    const int BA = BB * AA;     // 134400
    const int BN = BB * NN;     // 1024

    char* ws = (char*)d_ws;
    unsigned long long* pos_bits = (unsigned long long*)ws;  size_t off = (size_t)BA * 8;
    int*   cand_idx  = (int*)(ws + off);   off += (size_t)BN * TOPKK * 4;
    float* cand_ov   = (float*)(ws + off); off += (size_t)BN * TOPKK * 4;
    float* cand_al   = (float*)(ws + off); off += (size_t)BN * TOPKK * 4;
    int*   cand_cnt  = (int*)(ws + off);   off += (size_t)BN * 4;
    float* pos_align = (float*)(ws + off); off += (size_t)BN * 4;
    float* pos_ovv   = (float*)(ws + off); off += (size_t)BN * 4;
    float* atan_pd   = (float*)(ws + off); off += (size_t)BA * 4;
    float* atan_gt   = (float*)(ws + off);

    float* out_labels = (float*)d_out;
    float* out_bboxes = out_labels + BA;
    float* out_scores = out_bboxes + (size_t)BA * 4;
    float* out_fg     = out_scores + (size_t)BA * CC;
    float* out_tgt    = out_fg + BA;

    hipMemsetAsync(pos_bits, 0, (size_t)BA * 8, stream);

    k0_atan<<<(BA + 255) / 256, 256, 0, stream>>>(pd_bboxes, gt_bboxes, atan_pd, atan_gt);
    k1_build<<<BN, 256, 0, stream>>>(pd_scores, pd_bboxes, anc, gt_labels, lab_stride,
                                     gt_bboxes, mask_gt, atan_pd, atan_gt, pos_bits,
                                     cand_idx, cand_ov, cand_al, cand_cnt);
    k2_filter<<<(BA + 255) / 256, 256, 0, stream>>>(pd_bboxes, anc, gt_bboxes, mask_gt,
                                                    atan_pd, atan_gt, pos_bits);
    k3_rowmax<<<(BN + 255) / 256, 256, 0, stream>>>(pos_bits, cand_idx, cand_ov, cand_al,
                                                    cand_cnt, pos_align, pos_ovv);
    k4_out<<<(BA + 255) / 256, 256, 0, stream>>>(pos_bits, gt_labels, lab_stride, gt_bboxes,
                                                 cand_idx, cand_al, cand_cnt, pos_align, pos_ovv,
                                                 out_labels, out_bboxes, out_scores, out_fg, out_tgt);
}

// Round 3
// 73.732 us; speedup vs baseline: 1.5571x; 1.1869x over previous
//
#include <hip/hip_runtime.h>
#include <hip/hip_bf16.h>

#define BB 16
#define NN 64
#define AA 8400
#define CC 20
#define TOPKK 13
#define CAP 448
#define CH 8
#define CHUNK (AA / CH)   // 1050

__device__ __forceinline__ int inside_gt(float4 g, float2 a) {
    float d = fminf(fminf(a.x - g.x, a.y - g.y), fminf(g.z - a.x, g.w - a.y));
    return d > 1e-9f;
}

__device__ __forceinline__ float ciou_clip(float4 g, float4 p, float at_p, float at_g) {
    const float eps = 1e-7f;
    float w1 = g.z - g.x, h1 = g.w - g.y;
    float w2 = p.z - p.x, h2 = p.w - p.y;
    float ix = fmaxf(fminf(g.z, p.z) - fmaxf(g.x, p.x), 0.0f);
    float iy = fmaxf(fminf(g.w, p.w) - fmaxf(g.y, p.y), 0.0f);
    float inter = ix * iy;
    float uni = w1 * h1 + w2 * h2 - inter + eps;
    float iou = inter / uni;
    float cw = fmaxf(g.z, p.z) - fminf(g.x, p.x);
    float ch = fmaxf(g.w, p.w) - fminf(g.y, p.y);
    float c2 = cw * cw + ch * ch + eps;
    float dx = p.x + p.z - g.x - g.z;
    float dy = p.y + p.w - g.y - g.w;
    float rho2 = (dx * dx + dy * dy) * 0.25f;
    float at = at_p - at_g;
    float v = 0.40528473456935109f * (at * at);
    float alpha = v / (v - iou + 1.0000001f);
    return fmaxf(iou - (rho2 / c2 + v * alpha), 0.0f);
}

// K0: atan tables + pd_scores transpose ([b][a][c] -> [b][c][a]).
__global__ __launch_bounds__(256) void k0_prep(
    const float* __restrict__ pd_scores, const float4* __restrict__ pd_bboxes,
    const float4* __restrict__ gt_bboxes,
    float* __restrict__ atan_pd, float* __restrict__ atan_gt,
    float* __restrict__ scores_T)
{
    int i = blockIdx.x * 256 + threadIdx.x;
    if (i < BB * AA) {
        float4 p = pd_bboxes[i];
        atan_pd[i] = atanf((p.z - p.x) / ((p.w - p.y) + 1e-7f));
        int b = i / AA, a = i % AA;
        const float* src = pd_scores + (size_t)i * CC;
        float* dst = scores_T + (size_t)b * CC * AA + a;
        #pragma unroll
        for (int c = 0; c < CC; ++c) dst[(size_t)c * AA] = src[c];
    }
    if (i < BB * NN) {
        float4 g = gt_bboxes[i];
        atan_gt[i] = atanf((g.z - g.x) / ((g.w - g.y) + 1e-7f));
    }
}

// K1a: scan+compact. 8 chunk-blocks per (b,n) row; positives -> global list.
__global__ __launch_bounds__(256) void k1a_scan(
    const float* __restrict__ scores_T, const float4* __restrict__ pd_bboxes,
    const float2* __restrict__ anc, const int* __restrict__ gt_labels, int lab_stride,
    const float4* __restrict__ gt_bboxes, const float* __restrict__ mask_gt,
    const float* __restrict__ atan_pd, const float* __restrict__ atan_gt,
    int* __restrict__ row_cnt,
    float* __restrict__ g_val, float* __restrict__ g_ov, int* __restrict__ g_ai)
{
    int row = blockIdx.x >> 3;           // b*NN + n
    int chunk = blockIdx.x & (CH - 1);
    if (mask_gt[row] <= 0.0f) return;
    int b = row >> 6;
    float4 g = gt_bboxes[row];
    float at_g = atan_gt[row];
    int label = gt_labels[row * lab_stride];
    const float4* pb  = pd_bboxes + (size_t)b * AA;
    const float*  apd = atan_pd + (size_t)b * AA;
    const float*  sT  = scores_T + (size_t)b * CC * AA + (size_t)label * AA;
    int base = chunk * CHUNK;

    for (int a = base + threadIdx.x; a < base + CHUNK; a += 256) {
        float2 apnt = anc[a];
        if (!inside_gt(g, apnt)) continue;
        float4 p = pb[a];
        float ov = ciou_clip(g, p, apd[a], at_g);
        float o2 = ov * ov;
        float al = sT[a] * (o2 * o2 * o2);
        if (al > 0.0f) {
            int slot = atomicAdd(&row_cnt[row], 1);
            if (slot < CAP) {
                size_t o = (size_t)row * CAP + slot;
                g_val[o] = al; g_ov[o] = ov; g_ai[o] = a;
            }
        }
    }
}

// K1b: per-row top-13 over compacted list. 1 wave per row, register-resident.
__global__ __launch_bounds__(64) void k1b_topk(
    const float* __restrict__ scores_T, const float4* __restrict__ pd_bboxes,
    const float2* __restrict__ anc, const int* __restrict__ gt_labels, int lab_stride,
    const float4* __restrict__ gt_bboxes, const float* __restrict__ mask_gt,
    const float* __restrict__ atan_pd, const float* __restrict__ atan_gt,
    const int* __restrict__ row_cnt,
    const float* __restrict__ g_val, const float* __restrict__ g_ov,
    const int* __restrict__ g_ai,
    unsigned long long* __restrict__ pos_bits,
    int* __restrict__ cand_idx, float* __restrict__ cand_ov,
    float* __restrict__ cand_al, int* __restrict__ cand_cnt)
{
    int row = blockIdx.x;
    int b = row >> 6, n = row & 63;
    int lane = threadIdx.x;
    if (mask_gt[row] <= 0.0f) { if (lane == 0) cand_cnt[row] = 0; return; }

    int p = min(row_cnt[row], CAP);
    const float* gv = g_val + (size_t)row * CAP;
    const float* go = g_ov + (size_t)row * CAP;
    const int*   ga = g_ai + (size_t)row * CAP;

    float v[7]; int ai[7]; float ov[7];
    #pragma unroll
    for (int j = 0; j < 7; ++j) {
        int s = lane + j * 64;
        bool ok = s < p;
        v[j] = ok ? gv[s] : -1.0f;
        ai[j] = ok ? ga[s] : (1 << 30);
        ov[j] = ok ? go[s] : 0.0f;
    }

    int nr = min(p, TOPKK);
    for (int k = 0; k < nr; ++k) {
        float bv = -1.0f; int ba = 1 << 30; float bo = 0.0f;
        #pragma unroll
        for (int j = 0; j < 7; ++j)
            if (v[j] > bv || (v[j] == bv && ai[j] < ba)) { bv = v[j]; ba = ai[j]; bo = ov[j]; }
        #pragma unroll
        for (int s2 = 32; s2 > 0; s2 >>= 1) {
            float v2 = __shfl_xor(bv, s2);
            int   a2 = __shfl_xor(ba, s2);
            float o2 = __shfl_xor(bo, s2);
            if (v2 > bv || (v2 == bv && a2 < ba)) { bv = v2; ba = a2; bo = o2; }
        }
        if (lane == 0) {
            cand_idx[row * TOPKK + k] = ba;
            cand_ov[row * TOPKK + k]  = bo;
            cand_al[row * TOPKK + k]  = bv;
            atomicOr(&pos_bits[(size_t)b * AA + ba], 1ull << n);
        }
        #pragma unroll
        for (int j = 0; j < 7; ++j) if (ai[j] == ba) v[j] = -1.0f;
    }

    if (p < TOPKK) {
        // top_k admits (13-p) zeros at the smallest anchor indices (all in [0,32)).
        __shared__ float s_ov[32];
        __shared__ int   s_state[32];   // 0=positive, 1=zero outside, 2=zero inside
        if (lane < 32) {
            float4 g = gt_bboxes[row];
            float2 ap = anc[lane];
            int ins = inside_gt(g, ap);
            float o = 0.0f, al = 0.0f;
            if (ins) {
                float4 pp = pd_bboxes[(size_t)b * AA + lane];
                o = ciou_clip(g, pp, atan_pd[(size_t)b * AA + lane], atan_gt[row]);
                int label = gt_labels[row * lab_stride];
                float sc = scores_T[(size_t)b * CC * AA + (size_t)label * AA + lane];
                float o2 = o * o;
                al = sc * (o2 * o2 * o2);
            }
            s_ov[lane] = o;
            s_state[lane] = (al == 0.0f) ? (ins ? 2 : 1) : 0;
        }
        __syncthreads();
        if (lane == 0) {
            int nsel = nr;
            int need = TOPKK - p;
            for (int a = 0; a < 32 && need > 0; ++a) {
                if (s_state[a]) {
                    if (s_state[a] == 2) {
                        cand_idx[row * TOPKK + nsel] = a;
                        cand_ov[row * TOPKK + nsel]  = s_ov[a];
                        cand_al[row * TOPKK + nsel]  = 0.0f;
                        atomicOr(&pos_bits[(size_t)b * AA + a], 1ull << n);
                        nsel++;
                    }
                    need--;
                }
            }
            cand_cnt[row] = nsel;
        }
        return;
    }
    if (lane == 0) cand_cnt[row] = nr;
}

// K2: resolve multi-assigned anchors: keep only argmax_n overlaps (first-max).
__global__ __launch_bounds__(256) void k2_filter(
    const float4* __restrict__ pd_bboxes, const float2* __restrict__ anc,
    const float4* __restrict__ gt_bboxes, const float* __restrict__ mask_gt,
    const float* __restrict__ atan_pd, const float* __restrict__ atan_gt,
    unsigned long long* __restrict__ pos_bits)
{
    int i = blockIdx.x * 256 + threadIdx.x;
    if (i >= BB * AA) return;
    unsigned long long bits = pos_bits[i];
    if (__popcll(bits) <= 1) return;
    int b = i / AA, a = i % AA;
    float4 p = pd_bboxes[i];
    float2 ap = anc[a];
    float at_p = atan_pd[i];
    float best = -1.0f; int bn = 0;
    for (int n = 0; n < NN; ++n) {
        float ov = 0.0f;
        if (mask_gt[b * NN + n] > 0.0f) {
            float4 g = gt_bboxes[b * NN + n];
            if (inside_gt(g, ap))
                ov = ciou_clip(g, p, at_p, atan_gt[b * NN + n]);
        }
        if (ov > best) { best = ov; bn = n; }
    }
    pos_bits[i] = bits & (1ull << bn);
}

// K3: per-(b,n) pos_align / pos_ov over surviving candidates.
__global__ __launch_bounds__(256) void k3_rowmax(
    const unsigned long long* __restrict__ pos_bits, const int* __restrict__ cand_idx,
    const float* __restrict__ cand_ov, const float* __restrict__ cand_al,
    const int* __restrict__ cand_cnt,
    float* __restrict__ pos_align, float* __restrict__ pos_ovv)
{
    int row = blockIdx.x * 256 + threadIdx.x;
    if (row >= BB * NN) return;
    int b = row >> 6, n = row & 63;
    int cnt = cand_cnt[row];
    float pa = 0.0f, po = 0.0f;
    for (int i = 0; i < cnt; ++i) {
        int a = cand_idx[row * TOPKK + i];
        if ((pos_bits[(size_t)b * AA + a] >> n) & 1ull) {
            pa = fmaxf(pa, cand_al[row * TOPKK + i]);
            po = fmaxf(po, cand_ov[row * TOPKK + i]);
        }
    }
    pos_align[row] = pa;
    pos_ovv[row] = po;
}

// K4: final outputs.
__global__ __launch_bounds__(256) void k4_out(
    const unsigned long long* __restrict__ pos_bits, const int* __restrict__ gt_labels,
    int lab_stride, const float4* __restrict__ gt_bboxes,
    const int* __restrict__ cand_idx, const float* __restrict__ cand_al,
    const int* __restrict__ cand_cnt,
    const float* __restrict__ pos_align, const float* __restrict__ pos_ovv,
    float* __restrict__ out_labels, float* __restrict__ out_bboxes,
    float* __restrict__ out_scores, float* __restrict__ out_fg,
    float* __restrict__ out_tgt)
{
    int i = blockIdx.x * 256 + threadIdx.x;
    if (i >= BB * AA) return;
    int b = i / AA;
    unsigned long long bits = pos_bits[i];
    int fg = bits != 0ull;
    int tgt = fg ? (__ffsll((unsigned long long)bits) - 1) : 0;
    int row = b * NN + tgt;
    int label = gt_labels[row * lab_stride];
    label = label > 0 ? label : 0;
    float4 g = gt_bboxes[row];
    out_labels[i] = (float)label;
    ((float4*)out_bboxes)[i] = g;
    float norm = 0.0f;
    if (fg) {
        int cnt = cand_cnt[row];
        int a = i - b * AA;
        float al = 0.0f;
        for (int j = 0; j < cnt; ++j) {
            if (cand_idx[row * TOPKK + j] == a) { al = cand_al[row * TOPKK + j]; break; }
        }
        norm = (al * pos_ovv[row]) / (pos_align[row] + 1e-9f);
    }
    float* sc = out_scores + (size_t)i * CC;
    #pragma unroll
    for (int c = 0; c < CC; ++c) sc[c] = (c == label && fg) ? norm : 0.0f;
    out_fg[i] = fg ? 1.0f : 0.0f;
    out_tgt[i] = (float)tgt;
}

extern "C" void kernel_launch(void* const* d_in, const int* in_sizes, int n_in,
                              void* d_out, int out_size, void* d_ws, size_t ws_size,
                              hipStream_t stream) {
    const float*  pd_scores = (const float*)d_in[0];
    const float4* pd_bboxes = (const float4*)d_in[1];
    const float2* anc       = (const float2*)d_in[2];
    const int*    gt_labels = (const int*)d_in[3];
    const float4* gt_bboxes = (const float4*)d_in[4];
    const float*  mask_gt   = (const float*)d_in[5];
    int lab_stride = (in_sizes[3] == 2 * BB * NN) ? 2 : 1;  // int64 fallback

    const int BA = BB * AA;     // 134400
    const int BN = BB * NN;     // 1024

    char* ws = (char*)d_ws;
    unsigned long long* pos_bits = (unsigned long long*)ws;  size_t off = (size_t)BA * 8;
    int*   row_cnt   = (int*)(ws + off);   off += (size_t)BN * 4;   // memset with pos_bits
    int*   cand_idx  = (int*)(ws + off);   off += (size_t)BN * TOPKK * 4;
    float* cand_ov   = (float*)(ws + off); off += (size_t)BN * TOPKK * 4;
    float* cand_al   = (float*)(ws + off); off += (size_t)BN * TOPKK * 4;
    int*   cand_cnt  = (int*)(ws + off);   off += (size_t)BN * 4;
    float* pos_align = (float*)(ws + off); off += (size_t)BN * 4;
    float* pos_ovv   = (float*)(ws + off); off += (size_t)BN * 4;
    float* atan_pd   = (float*)(ws + off); off += (size_t)BA * 4;
    float* atan_gt   = (float*)(ws + off); off += (size_t)BN * 4;
    float* g_val     = (float*)(ws + off); off += (size_t)BN * CAP * 4;
    float* g_ov      = (float*)(ws + off); off += (size_t)BN * CAP * 4;
    int*   g_ai      = (int*)(ws + off);   off += (size_t)BN * CAP * 4;
    float* scores_T  = (float*)(ws + off);

    float* out_labels = (float*)d_out;
    float* out_bboxes = out_labels + BA;
    float* out_scores = out_bboxes + (size_t)BA * 4;
    float* out_fg     = out_scores + (size_t)BA * CC;
    float* out_tgt    = out_fg + BA;

    hipMemsetAsync(pos_bits, 0, (size_t)BA * 8 + (size_t)BN * 4, stream);

    k0_prep<<<(BA + 255) / 256, 256, 0, stream>>>(pd_scores, pd_bboxes, gt_bboxes,
                                                  atan_pd, atan_gt, scores_T);
    k1a_scan<<<BN * CH, 256, 0, stream>>>(scores_T, pd_bboxes, anc, gt_labels, lab_stride,
                                          gt_bboxes, mask_gt, atan_pd, atan_gt,
                                          row_cnt, g_val, g_ov, g_ai);
    k1b_topk<<<BN, 64, 0, stream>>>(scores_T, pd_bboxes, anc, gt_labels, lab_stride,
                                    gt_bboxes, mask_gt, atan_pd, atan_gt,
                                    row_cnt, g_val, g_ov, g_ai, pos_bits,
                                    cand_idx, cand_ov, cand_al, cand_cnt);
    k2_filter<<<(BA + 255) / 256, 256, 0, stream>>>(pd_bboxes, anc, gt_bboxes, mask_gt,
                                                    atan_pd, atan_gt, pos_bits);
    k3_rowmax<<<(BN + 255) / 256, 256, 0, stream>>>(pos_bits, cand_idx, cand_ov, cand_al,
                                                    cand_cnt, pos_align, pos_ovv);
    k4_out<<<(BA + 255) / 256, 256, 0, stream>>>(pos_bits, gt_labels, lab_stride, gt_bboxes,
                                                 cand_idx, cand_al, cand_cnt, pos_align, pos_ovv,
                                                 out_labels, out_bboxes, out_scores, out_fg, out_tgt);
}

// Round 4
// 69.642 us; speedup vs baseline: 1.6485x; 1.0587x over previous
//
#include <hip/hip_runtime.h>
#include <hip/hip_bf16.h>

#define BB 16
#define NN 64
#define AA 8400
#define CC 20
#define TOPKK 13
#define CAP 448
#define CH 8
#define CHUNK (AA / CH)   // 1050

__device__ __forceinline__ int inside_gt(float4 g, float2 a) {
    float d = fminf(fminf(a.x - g.x, a.y - g.y), fminf(g.z - a.x, g.w - a.y));
    return d > 1e-9f;
}

__device__ __forceinline__ float ciou_clip(float4 g, float4 p, float at_p, float at_g) {
    const float eps = 1e-7f;
    float w1 = g.z - g.x, h1 = g.w - g.y;
    float w2 = p.z - p.x, h2 = p.w - p.y;
    float ix = fmaxf(fminf(g.z, p.z) - fmaxf(g.x, p.x), 0.0f);
    float iy = fmaxf(fminf(g.w, p.w) - fmaxf(g.y, p.y), 0.0f);
    float inter = ix * iy;
    float uni = w1 * h1 + w2 * h2 - inter + eps;
    float iou = inter / uni;
    float cw = fmaxf(g.z, p.z) - fminf(g.x, p.x);
    float ch = fmaxf(g.w, p.w) - fminf(g.y, p.y);
    float c2 = cw * cw + ch * ch + eps;
    float dx = p.x + p.z - g.x - g.z;
    float dy = p.y + p.w - g.y - g.w;
    float rho2 = (dx * dx + dy * dy) * 0.25f;
    float at = at_p - at_g;
    float v = 0.40528473456935109f * (at * at);
    float alpha = v / (v - iou + 1.0000001f);
    return fmaxf(iou - (rho2 / c2 + v * alpha), 0.0f);
}

// K0: atan tables + pd_scores transpose + zero pos_bits/row_cnt.
__global__ __launch_bounds__(256) void k0_prep(
    const float* __restrict__ pd_scores, const float4* __restrict__ pd_bboxes,
    const float4* __restrict__ gt_bboxes,
    float* __restrict__ atan_pd, float* __restrict__ atan_gt,
    float* __restrict__ scores_T,
    unsigned long long* __restrict__ pos_bits, int* __restrict__ row_cnt)
{
    int i = blockIdx.x * 256 + threadIdx.x;
    if (i < BB * AA) {
        pos_bits[i] = 0ull;
        float4 p = pd_bboxes[i];
        atan_pd[i] = atanf((p.z - p.x) / ((p.w - p.y) + 1e-7f));
        int b = i / AA, a = i % AA;
        const float* src = pd_scores + (size_t)i * CC;
        float* dst = scores_T + (size_t)b * CC * AA + a;
        #pragma unroll
        for (int c = 0; c < CC; ++c) dst[(size_t)c * AA] = src[c];
    }
    if (i < BB * NN) {
        row_cnt[i] = 0;
        float4 g = gt_bboxes[i];
        atan_gt[i] = atanf((g.z - g.x) / ((g.w - g.y) + 1e-7f));
    }
}

// K1a: scan+compact. 8 chunk-blocks per (b,n) row; positives -> global list.
__global__ __launch_bounds__(256) void k1a_scan(
    const float* __restrict__ scores_T, const float4* __restrict__ pd_bboxes,
    const float2* __restrict__ anc, const int* __restrict__ gt_labels, int lab_stride,
    const float4* __restrict__ gt_bboxes, const float* __restrict__ mask_gt,
    const float* __restrict__ atan_pd, const float* __restrict__ atan_gt,
    int* __restrict__ row_cnt,
    float* __restrict__ g_val, float* __restrict__ g_ov, int* __restrict__ g_ai)
{
    int row = blockIdx.x >> 3;           // b*NN + n
    int chunk = blockIdx.x & (CH - 1);
    if (mask_gt[row] <= 0.0f) return;
    int b = row >> 6;
    float4 g = gt_bboxes[row];
    float at_g = atan_gt[row];
    int label = gt_labels[row * lab_stride];
    const float4* pb  = pd_bboxes + (size_t)b * AA;
    const float*  apd = atan_pd + (size_t)b * AA;
    const float*  sT  = scores_T + (size_t)b * CC * AA + (size_t)label * AA;
    int base = chunk * CHUNK;

    for (int a = base + threadIdx.x; a < base + CHUNK; a += 256) {
        float2 apnt = anc[a];
        if (!inside_gt(g, apnt)) continue;
        float4 p = pb[a];
        float ov = ciou_clip(g, p, apd[a], at_g);
        float o2 = ov * ov;
        float al = sT[a] * (o2 * o2 * o2);
        if (al > 0.0f) {
            int slot = atomicAdd(&row_cnt[row], 1);
            if (slot < CAP) {
                size_t o = (size_t)row * CAP + slot;
                g_val[o] = al; g_ov[o] = ov; g_ai[o] = a;
            }
        }
    }
}

// K1b: per-row top-13 over compacted list. 1 wave per row, register-resident.
__global__ __launch_bounds__(64) void k1b_topk(
    const float* __restrict__ scores_T, const float4* __restrict__ pd_bboxes,
    const float2* __restrict__ anc, const int* __restrict__ gt_labels, int lab_stride,
    const float4* __restrict__ gt_bboxes, const float* __restrict__ mask_gt,
    const float* __restrict__ atan_pd, const float* __restrict__ atan_gt,
    const int* __restrict__ row_cnt,
    const float* __restrict__ g_val, const float* __restrict__ g_ov,
    const int* __restrict__ g_ai,
    unsigned long long* __restrict__ pos_bits,
    int* __restrict__ cand_idx, float* __restrict__ cand_ov,
    float* __restrict__ cand_al, int* __restrict__ cand_cnt)
{
    int row = blockIdx.x;
    int b = row >> 6, n = row & 63;
    int lane = threadIdx.x;
    if (mask_gt[row] <= 0.0f) { if (lane == 0) cand_cnt[row] = 0; return; }

    int p = min(row_cnt[row], CAP);
    const float* gv = g_val + (size_t)row * CAP;
    const float* go = g_ov + (size_t)row * CAP;
    const int*   ga = g_ai + (size_t)row * CAP;

    float v[7]; int ai[7]; float ov[7];
    #pragma unroll
    for (int j = 0; j < 7; ++j) {
        int s = lane + j * 64;
        bool ok = s < p;
        v[j] = ok ? gv[s] : -1.0f;
        ai[j] = ok ? ga[s] : (1 << 30);
        ov[j] = ok ? go[s] : 0.0f;
    }

    int nr = min(p, TOPKK);
    for (int k = 0; k < nr; ++k) {
        float bv = -1.0f; int ba = 1 << 30; float bo = 0.0f;
        #pragma unroll
        for (int j = 0; j < 7; ++j)
            if (v[j] > bv || (v[j] == bv && ai[j] < ba)) { bv = v[j]; ba = ai[j]; bo = ov[j]; }
        #pragma unroll
        for (int s2 = 32; s2 > 0; s2 >>= 1) {
            float v2 = __shfl_xor(bv, s2);
            int   a2 = __shfl_xor(ba, s2);
            float o2 = __shfl_xor(bo, s2);
            if (v2 > bv || (v2 == bv && a2 < ba)) { bv = v2; ba = a2; bo = o2; }
        }
        if (lane == 0) {
            cand_idx[row * TOPKK + k] = ba;
            cand_ov[row * TOPKK + k]  = bo;
            cand_al[row * TOPKK + k]  = bv;
            atomicOr(&pos_bits[(size_t)b * AA + ba], 1ull << n);
        }
        #pragma unroll
        for (int j = 0; j < 7; ++j) if (ai[j] == ba) v[j] = -1.0f;
    }

    if (p < TOPKK) {
        // top_k admits (13-p) zeros at the smallest anchor indices (all in [0,32)).
        __shared__ float s_ov[32];
        __shared__ int   s_state[32];   // 0=positive, 1=zero outside, 2=zero inside
        if (lane < 32) {
            float4 g = gt_bboxes[row];
            float2 ap = anc[lane];
            int ins = inside_gt(g, ap);
            float o = 0.0f, al = 0.0f;
            if (ins) {
                float4 pp = pd_bboxes[(size_t)b * AA + lane];
                o = ciou_clip(g, pp, atan_pd[(size_t)b * AA + lane], atan_gt[row]);
                int label = gt_labels[row * lab_stride];
                float sc = scores_T[(size_t)b * CC * AA + (size_t)label * AA + lane];
                float o2 = o * o;
                al = sc * (o2 * o2 * o2);
            }
            s_ov[lane] = o;
            s_state[lane] = (al == 0.0f) ? (ins ? 2 : 1) : 0;
        }
        __syncthreads();
        if (lane == 0) {
            int nsel = nr;
            int need = TOPKK - p;
            for (int a = 0; a < 32 && need > 0; ++a) {
                if (s_state[a]) {
                    if (s_state[a] == 2) {
                        cand_idx[row * TOPKK + nsel] = a;
                        cand_ov[row * TOPKK + nsel]  = s_ov[a];
                        cand_al[row * TOPKK + nsel]  = 0.0f;
                        atomicOr(&pos_bits[(size_t)b * AA + a], 1ull << n);
                        nsel++;
                    }
                    need--;
                }
            }
            cand_cnt[row] = nsel;
        }
        return;
    }
    if (lane == 0) cand_cnt[row] = nr;
}

// K2: resolve multi-assigned anchors: keep only argmax_n overlaps (first-max).
__global__ __launch_bounds__(256) void k2_filter(
    const float4* __restrict__ pd_bboxes, const float2* __restrict__ anc,
    const float4* __restrict__ gt_bboxes, const float* __restrict__ mask_gt,
    const float* __restrict__ atan_pd, const float* __restrict__ atan_gt,
    unsigned long long* __restrict__ pos_bits)
{
    int i = blockIdx.x * 256 + threadIdx.x;
    if (i >= BB * AA) return;
    unsigned long long bits = pos_bits[i];
    if (__popcll(bits) <= 1) return;
    int b = i / AA, a = i % AA;
    float4 p = pd_bboxes[i];
    float2 ap = anc[a];
    float at_p = atan_pd[i];
    float best = -1.0f; int bn = 0;
    for (int n = 0; n < NN; ++n) {
        float ov = 0.0f;
        if (mask_gt[b * NN + n] > 0.0f) {
            float4 g = gt_bboxes[b * NN + n];
            if (inside_gt(g, ap))
                ov = ciou_clip(g, p, at_p, atan_gt[b * NN + n]);
        }
        if (ov > best) { best = ov; bn = n; }
    }
    pos_bits[i] = bits & (1ull << bn);
}

// K3: per-(b,n) pos_align / pos_ov over surviving candidates.
__global__ __launch_bounds__(256) void k3_rowmax(
    const unsigned long long* __restrict__ pos_bits, const int* __restrict__ cand_idx,
    const float* __restrict__ cand_ov, const float* __restrict__ cand_al,
    const int* __restrict__ cand_cnt,
    float* __restrict__ pos_align, float* __restrict__ pos_ovv)
{
    int row = blockIdx.x * 256 + threadIdx.x;
    if (row >= BB * NN) return;
    int b = row >> 6, n = row & 63;
    int cnt = cand_cnt[row];
    float pa = 0.0f, po = 0.0f;
    for (int i = 0; i < cnt; ++i) {
        int a = cand_idx[row * TOPKK + i];
        if ((pos_bits[(size_t)b * AA + a] >> n) & 1ull) {
            pa = fmaxf(pa, cand_al[row * TOPKK + i]);
            po = fmaxf(po, cand_ov[row * TOPKK + i]);
        }
    }
    pos_align[row] = pa;
    pos_ovv[row] = po;
}

// K4: final outputs.
__global__ __launch_bounds__(256) void k4_out(
    const unsigned long long* __restrict__ pos_bits, const int* __restrict__ gt_labels,
    int lab_stride, const float4* __restrict__ gt_bboxes,
    const int* __restrict__ cand_idx, const float* __restrict__ cand_al,
    const int* __restrict__ cand_cnt,
    const float* __restrict__ pos_align, const float* __restrict__ pos_ovv,
    float* __restrict__ out_labels, float* __restrict__ out_bboxes,
    float* __restrict__ out_scores, float* __restrict__ out_fg,
    float* __restrict__ out_tgt)
{
    int i = blockIdx.x * 256 + threadIdx.x;
    if (i >= BB * AA) return;
    int b = i / AA;
    unsigned long long bits = pos_bits[i];
    int fg = bits != 0ull;
    int tgt = fg ? (__ffsll((unsigned long long)bits) - 1) : 0;
    int row = b * NN + tgt;
    int label = gt_labels[row * lab_stride];
    label = label > 0 ? label : 0;
    float4 g = gt_bboxes[row];
    out_labels[i] = (float)label;
    ((float4*)out_bboxes)[i] = g;
    float norm = 0.0f;
    if (fg) {
        int cnt = cand_cnt[row];
        int a = i - b * AA;
        float al = 0.0f;
        for (int j = 0; j < cnt; ++j) {
            if (cand_idx[row * TOPKK + j] == a) { al = cand_al[row * TOPKK + j]; break; }
        }
        norm = (al * pos_ovv[row]) / (pos_align[row] + 1e-9f);
    }
    float* sc = out_scores + (size_t)i * CC;
    #pragma unroll
    for (int c = 0; c < CC; ++c) sc[c] = (c == label && fg) ? norm : 0.0f;
    out_fg[i] = fg ? 1.0f : 0.0f;
    out_tgt[i] = (float)tgt;
}

extern "C" void kernel_launch(void* const* d_in, const int* in_sizes, int n_in,
                              void* d_out, int out_size, void* d_ws, size_t ws_size,
                              hipStream_t stream) {
    const float*  pd_scores = (const float*)d_in[0];
    const float4* pd_bboxes = (const float4*)d_in[1];
    const float2* anc       = (const float2*)d_in[2];
    const int*    gt_labels = (const int*)d_in[3];
    const float4* gt_bboxes = (const float4*)d_in[4];
    const float*  mask_gt   = (const float*)d_in[5];
    int lab_stride = (in_sizes[3] == 2 * BB * NN) ? 2 : 1;  // int64 fallback

    const int BA = BB * AA;     // 134400
    const int BN = BB * NN;     // 1024

    char* ws = (char*)d_ws;
    unsigned long long* pos_bits = (unsigned long long*)ws;  size_t off = (size_t)BA * 8;
    int*   row_cnt   = (int*)(ws + off);   off += (size_t)BN * 4;
    int*   cand_idx  = (int*)(ws + off);   off += (size_t)BN * TOPKK * 4;
    float* cand_ov   = (float*)(ws + off); off += (size_t)BN * TOPKK * 4;
    float* cand_al   = (float*)(ws + off); off += (size_t)BN * TOPKK * 4;
    int*   cand_cnt  = (int*)(ws + off);   off += (size_t)BN * 4;
    float* pos_align = (float*)(ws + off); off += (size_t)BN * 4;
    float* pos_ovv   = (float*)(ws + off); off += (size_t)BN * 4;
    float* atan_pd   = (float*)(ws + off); off += (size_t)BA * 4;
    float* atan_gt   = (float*)(ws + off); off += (size_t)BN * 4;
    float* g_val     = (float*)(ws + off); off += (size_t)BN * CAP * 4;
    float* g_ov      = (float*)(ws + off); off += (size_t)BN * CAP * 4;
    int*   g_ai      = (int*)(ws + off);   off += (size_t)BN * CAP * 4;
    float* scores_T  = (float*)(ws + off);

    float* out_labels = (float*)d_out;
    float* out_bboxes = out_labels + BA;
    float* out_scores = out_bboxes + (size_t)BA * 4;
    float* out_fg     = out_scores + (size_t)BA * CC;
    float* out_tgt    = out_fg + BA;

    k0_prep<<<(BA + 255) / 256, 256, 0, stream>>>(pd_scores, pd_bboxes, gt_bboxes,
                                                  atan_pd, atan_gt, scores_T,
                                                  pos_bits, row_cnt);
    k1a_scan<<<BN * CH, 256, 0, stream>>>(scores_T, pd_bboxes, anc, gt_labels, lab_stride,
                                          gt_bboxes, mask_gt, atan_pd, atan_gt,
                                          row_cnt, g_val, g_ov, g_ai);
    k1b_topk<<<BN, 64, 0, stream>>>(scores_T, pd_bboxes, anc, gt_labels, lab_stride,
                                    gt_bboxes, mask_gt, atan_pd, atan_gt,
                                    row_cnt, g_val, g_ov, g_ai, pos_bits,
                                    cand_idx, cand_ov, cand_al, cand_cnt);
    k2_filter<<<(BA + 255) / 256, 256, 0, stream>>>(pd_bboxes, anc, gt_bboxes, mask_gt,
                                                    atan_pd, atan_gt, pos_bits);
    k3_rowmax<<<(BN + 255) / 256, 256, 0, stream>>>(pos_bits, cand_idx, cand_ov, cand_al,
                                                    cand_cnt, pos_align, pos_ovv);
    k4_out<<<(BA + 255) / 256, 256, 0, stream>>>(pos_bits, gt_labels, lab_stride, gt_bboxes,
                                                 cand_idx, cand_al, cand_cnt, pos_align, pos_ovv,
                                                 out_labels, out_bboxes, out_scores, out_fg, out_tgt);
}

// Round 5
// 64.951 us; speedup vs baseline: 1.7676x; 1.0722x over previous
//
#include <hip/hip_runtime.h>
#include <hip/hip_bf16.h>

#define BB 16
#define NN 64
#define AA 8400
#define CC 20
#define TOPKK 13
#define CAP 448
#define CH 8
#define CHUNK (AA / CH)   // 1050

__device__ __forceinline__ int inside_gt(float4 g, float2 a) {
    float d = fminf(fminf(a.x - g.x, a.y - g.y), fminf(g.z - a.x, g.w - a.y));
    return d > 1e-9f;
}

__device__ __forceinline__ float atan_wh(float4 bx) {
    return atanf((bx.z - bx.x) / ((bx.w - bx.y) + 1e-7f));
}

__device__ __forceinline__ float ciou_clip(float4 g, float4 p, float at_p, float at_g) {
    const float eps = 1e-7f;
    float w1 = g.z - g.x, h1 = g.w - g.y;
    float w2 = p.z - p.x, h2 = p.w - p.y;
    float ix = fmaxf(fminf(g.z, p.z) - fmaxf(g.x, p.x), 0.0f);
    float iy = fmaxf(fminf(g.w, p.w) - fmaxf(g.y, p.y), 0.0f);
    float inter = ix * iy;
    float uni = w1 * h1 + w2 * h2 - inter + eps;
    float iou = inter / uni;
    float cw = fmaxf(g.z, p.z) - fminf(g.x, p.x);
    float ch = fmaxf(g.w, p.w) - fminf(g.y, p.y);
    float c2 = cw * cw + ch * ch + eps;
    float dx = p.x + p.z - g.x - g.z;
    float dy = p.y + p.w - g.y - g.w;
    float rho2 = (dx * dx + dy * dy) * 0.25f;
    float at = at_p - at_g;
    float v = 0.40528473456935109f * (at * at);
    float alpha = v / (v - iou + 1.0000001f);
    return fmaxf(iou - (rho2 / c2 + v * alpha), 0.0f);
}

// K0: zero pos_bits + row_cnt (full-width grid, ~1 MB).
__global__ __launch_bounds__(256) void k0_zero(
    unsigned long long* __restrict__ pos_bits, int* __restrict__ row_cnt)
{
    int i = blockIdx.x * 256 + threadIdx.x;
    if (i < BB * AA) pos_bits[i] = 0ull;
    if (i < BB * NN) row_cnt[i] = 0;
}

// K1a: scan+compact. 8 chunk-blocks per (b,n) row; positives -> global list.
__global__ __launch_bounds__(256) void k1a_scan(
    const float* __restrict__ pd_scores, const float4* __restrict__ pd_bboxes,
    const float2* __restrict__ anc, const int* __restrict__ gt_labels, int lab_stride,
    const float4* __restrict__ gt_bboxes, const float* __restrict__ mask_gt,
    int* __restrict__ row_cnt,
    float* __restrict__ g_val, float* __restrict__ g_ov, int* __restrict__ g_ai)
{
    int row = blockIdx.x >> 3;           // b*NN + n
    int chunk = blockIdx.x & (CH - 1);
    if (mask_gt[row] <= 0.0f) return;
    int b = row >> 6;
    float4 g = gt_bboxes[row];
    float at_g = atan_wh(g);
    int label = gt_labels[row * lab_stride];
    const float4* pb = pd_bboxes + (size_t)b * AA;
    const float*  ps = pd_scores + ((size_t)b * AA) * CC + label;
    int base = chunk * CHUNK;

    for (int a = base + threadIdx.x; a < base + CHUNK; a += 256) {
        float2 apnt = anc[a];
        if (!inside_gt(g, apnt)) continue;
        float4 p = pb[a];
        float ov = ciou_clip(g, p, atan_wh(p), at_g);
        float o2 = ov * ov;
        float al = ps[(size_t)a * CC] * (o2 * o2 * o2);
        if (al > 0.0f) {
            int slot = atomicAdd(&row_cnt[row], 1);
            if (slot < CAP) {
                size_t o = (size_t)row * CAP + slot;
                g_val[o] = al; g_ov[o] = ov; g_ai[o] = a;
            }
        }
    }
}

// K1b: per-row top-13 over compacted list. 1 wave per row, register-resident.
__global__ __launch_bounds__(64) void k1b_topk(
    const float* __restrict__ pd_scores, const float4* __restrict__ pd_bboxes,
    const float2* __restrict__ anc, const int* __restrict__ gt_labels, int lab_stride,
    const float4* __restrict__ gt_bboxes, const float* __restrict__ mask_gt,
    const int* __restrict__ row_cnt,
    const float* __restrict__ g_val, const float* __restrict__ g_ov,
    const int* __restrict__ g_ai,
    unsigned long long* __restrict__ pos_bits,
    int* __restrict__ cand_idx, float* __restrict__ cand_ov,
    float* __restrict__ cand_al, int* __restrict__ cand_cnt)
{
    int row = blockIdx.x;
    int b = row >> 6, n = row & 63;
    int lane = threadIdx.x;
    if (mask_gt[row] <= 0.0f) { if (lane == 0) cand_cnt[row] = 0; return; }

    int p = min(row_cnt[row], CAP);
    const float* gv = g_val + (size_t)row * CAP;
    const float* go = g_ov + (size_t)row * CAP;
    const int*   ga = g_ai + (size_t)row * CAP;

    float v[7]; int ai[7]; float ov[7];
    #pragma unroll
    for (int j = 0; j < 7; ++j) {
        int s = lane + j * 64;
        bool ok = s < p;
        v[j] = ok ? gv[s] : -1.0f;
        ai[j] = ok ? ga[s] : (1 << 30);
        ov[j] = ok ? go[s] : 0.0f;
    }

    int nr = min(p, TOPKK);
    for (int k = 0; k < nr; ++k) {
        float bv = -1.0f; int ba = 1 << 30; float bo = 0.0f;
        #pragma unroll
        for (int j = 0; j < 7; ++j)
            if (v[j] > bv || (v[j] == bv && ai[j] < ba)) { bv = v[j]; ba = ai[j]; bo = ov[j]; }
        #pragma unroll
        for (int s2 = 32; s2 > 0; s2 >>= 1) {
            float v2 = __shfl_xor(bv, s2);
            int   a2 = __shfl_xor(ba, s2);
            float o2 = __shfl_xor(bo, s2);
            if (v2 > bv || (v2 == bv && a2 < ba)) { bv = v2; ba = a2; bo = o2; }
        }
        if (lane == 0) {
            cand_idx[row * TOPKK + k] = ba;
            cand_ov[row * TOPKK + k]  = bo;
            cand_al[row * TOPKK + k]  = bv;
            atomicOr(&pos_bits[(size_t)b * AA + ba], 1ull << n);
        }
        #pragma unroll
        for (int j = 0; j < 7; ++j) if (ai[j] == ba) v[j] = -1.0f;
    }

    if (p < TOPKK) {
        // top_k admits (13-p) zeros at the smallest anchor indices (all in [0,32)).
        __shared__ float s_ov[32];
        __shared__ int   s_state[32];   // 0=positive, 1=zero outside, 2=zero inside
        if (lane < 32) {
            float4 g = gt_bboxes[row];
            float2 ap = anc[lane];
            int ins = inside_gt(g, ap);
            float o = 0.0f, al = 0.0f;
            if (ins) {
                float4 pp = pd_bboxes[(size_t)b * AA + lane];
                o = ciou_clip(g, pp, atan_wh(pp), atan_wh(g));
                int label = gt_labels[row * lab_stride];
                float sc = pd_scores[((size_t)b * AA + lane) * CC + label];
                float o2 = o * o;
                al = sc * (o2 * o2 * o2);
            }
            s_ov[lane] = o;
            s_state[lane] = (al == 0.0f) ? (ins ? 2 : 1) : 0;
        }
        __syncthreads();
        if (lane == 0) {
            int nsel = nr;
            int need = TOPKK - p;
            for (int a = 0; a < 32 && need > 0; ++a) {
                if (s_state[a]) {
                    if (s_state[a] == 2) {
                        cand_idx[row * TOPKK + nsel] = a;
                        cand_ov[row * TOPKK + nsel]  = s_ov[a];
                        cand_al[row * TOPKK + nsel]  = 0.0f;
                        atomicOr(&pos_bits[(size_t)b * AA + a], 1ull << n);
                        nsel++;
                    }
                    need--;
                }
            }
            cand_cnt[row] = nsel;
        }
        return;
    }
    if (lane == 0) cand_cnt[row] = nr;
}

// K2: resolve multi-assigned anchors: keep only argmax_n overlaps (first-max).
__global__ __launch_bounds__(256) void k2_filter(
    const float4* __restrict__ pd_bboxes, const float2* __restrict__ anc,
    const float4* __restrict__ gt_bboxes, const float* __restrict__ mask_gt,
    unsigned long long* __restrict__ pos_bits)
{
    int i = blockIdx.x * 256 + threadIdx.x;
    if (i >= BB * AA) return;
    unsigned long long bits = pos_bits[i];
    if (__popcll(bits) <= 1) return;
    int b = i / AA, a = i % AA;
    float4 p = pd_bboxes[i];
    float2 ap = anc[a];
    float at_p = atan_wh(p);
    float best = -1.0f; int bn = 0;
    for (int n = 0; n < NN; ++n) {
        float ov = 0.0f;
        if (mask_gt[b * NN + n] > 0.0f) {
            float4 g = gt_bboxes[b * NN + n];
            if (inside_gt(g, ap))
                ov = ciou_clip(g, p, at_p, atan_wh(g));
        }
        if (ov > best) { best = ov; bn = n; }
    }
    pos_bits[i] = bits & (1ull << bn);
}

// K4: final outputs (k3 folded in: per-thread row max over <=13 cands).
__global__ __launch_bounds__(256) void k4_out(
    const unsigned long long* __restrict__ pos_bits, const int* __restrict__ gt_labels,
    int lab_stride, const float4* __restrict__ gt_bboxes,
    const int* __restrict__ cand_idx, const float* __restrict__ cand_ov,
    const float* __restrict__ cand_al, const int* __restrict__ cand_cnt,
    float* __restrict__ out_labels, float* __restrict__ out_bboxes,
    float* __restrict__ out_scores, float* __restrict__ out_fg,
    float* __restrict__ out_tgt)
{
    int i = blockIdx.x * 256 + threadIdx.x;
    if (i >= BB * AA) return;
    int b = i / AA;
    unsigned long long bits = pos_bits[i];
    int fg = bits != 0ull;
    int tgt = fg ? (__ffsll((unsigned long long)bits) - 1) : 0;
    int row = b * NN + tgt;
    int label = gt_labels[row * lab_stride];
    label = label > 0 ? label : 0;
    float4 g = gt_bboxes[row];
    out_labels[i] = (float)label;
    ((float4*)out_bboxes)[i] = g;
    float norm = 0.0f;
    if (fg) {
        int cnt = cand_cnt[row];
        int a = i - b * AA;
        int n = tgt;
        float al = 0.0f, pa = 0.0f, po = 0.0f;
        for (int j = 0; j < cnt; ++j) {
            int aj = cand_idx[row * TOPKK + j];
            if ((pos_bits[(size_t)b * AA + aj] >> n) & 1ull) {
                pa = fmaxf(pa, cand_al[row * TOPKK + j]);
                po = fmaxf(po, cand_ov[row * TOPKK + j]);
            }
            if (aj == a) al = cand_al[row * TOPKK + j];
        }
        norm = (al * po) / (pa + 1e-9f);
    }
    float* sc = out_scores + (size_t)i * CC;
    #pragma unroll
    for (int c = 0; c < CC; ++c) sc[c] = (c == label && fg) ? norm : 0.0f;
    out_fg[i] = fg ? 1.0f : 0.0f;
    out_tgt[i] = (float)tgt;
}

extern "C" void kernel_launch(void* const* d_in, const int* in_sizes, int n_in,
                              void* d_out, int out_size, void* d_ws, size_t ws_size,
                              hipStream_t stream) {
    const float*  pd_scores = (const float*)d_in[0];
    const float4* pd_bboxes = (const float4*)d_in[1];
    const float2* anc       = (const float2*)d_in[2];
    const int*    gt_labels = (const int*)d_in[3];
    const float4* gt_bboxes = (const float4*)d_in[4];
    const float*  mask_gt   = (const float*)d_in[5];
    int lab_stride = (in_sizes[3] == 2 * BB * NN) ? 2 : 1;  // int64 fallback

    const int BA = BB * AA;     // 134400
    const int BN = BB * NN;     // 1024

    char* ws = (char*)d_ws;
    unsigned long long* pos_bits = (unsigned long long*)ws;  size_t off = (size_t)BA * 8;
    int*   row_cnt   = (int*)(ws + off);   off += (size_t)BN * 4;
    int*   cand_idx  = (int*)(ws + off);   off += (size_t)BN * TOPKK * 4;
    float* cand_ov   = (float*)(ws + off); off += (size_t)BN * TOPKK * 4;
    float* cand_al   = (float*)(ws + off); off += (size_t)BN * TOPKK * 4;
    int*   cand_cnt  = (int*)(ws + off);   off += (size_t)BN * 4;
    float* g_val     = (float*)(ws + off); off += (size_t)BN * CAP * 4;
    float* g_ov      = (float*)(ws + off); off += (size_t)BN * CAP * 4;
    int*   g_ai      = (int*)(ws + off);

    float* out_labels = (float*)d_out;
    float* out_bboxes = out_labels + BA;
    float* out_scores = out_bboxes + (size_t)BA * 4;
    float* out_fg     = out_scores + (size_t)BA * CC;
    float* out_tgt    = out_fg + BA;

    k0_zero<<<(BA + 255) / 256, 256, 0, stream>>>(pos_bits, row_cnt);
    k1a_scan<<<BN * CH, 256, 0, stream>>>(pd_scores, pd_bboxes, anc, gt_labels, lab_stride,
                                          gt_bboxes, mask_gt, row_cnt, g_val, g_ov, g_ai);
    k1b_topk<<<BN, 64, 0, stream>>>(pd_scores, pd_bboxes, anc, gt_labels, lab_stride,
                                    gt_bboxes, mask_gt, row_cnt, g_val, g_ov, g_ai, pos_bits,
                                    cand_idx, cand_ov, cand_al, cand_cnt);
    k2_filter<<<(BA + 255) / 256, 256, 0, stream>>>(pd_bboxes, anc, gt_bboxes, mask_gt, pos_bits);
    k4_out<<<(BA + 255) / 256, 256, 0, stream>>>(pos_bits, gt_labels, lab_stride, gt_bboxes,
                                                 cand_idx, cand_ov, cand_al, cand_cnt,
                                                 out_labels, out_bboxes, out_scores, out_fg, out_tgt);
}